// Round 9
// baseline (36.777 us; speedup 1.0000x reference)
//
#include <hip/hip_runtime.h>
#include <math.h>
#include <limits.h>

#define BB 128
#define KK 2048
#define NN 4
#define CC 64
#define DD 3
#define TA 512          // threads in crit_all (8 waves)
#define KPT (KK/TA)     // 4 k's per thread
#define NW (TA/64)      // 8 waves

// ws layout (float words): [0, BB*3) per-batch loss partials {loc,cls,obj}

// ---- fast approximations: COST MATRIX ONLY (losses use accurate libm) ----
__device__ __forceinline__ float acospi_fast(float x) {
    // Hastings: acos(x) ~ sqrt(1-x)*p(x), abs err ~6.7e-5 rad; divided by pi.
    float ax = fabsf(x);
    float p = ((-0.0187293f*ax + 0.0742610f)*ax - 0.2121144f)*ax + 1.5707288f;
    float r = sqrtf(1.f - ax) * p;
    r = (x >= 0.f) ? r : 3.14159274f - r;
    return r * 0.31830988618379067f;
}

// CLS_CW * focal_pos term of the cost (fast-math form; cost path only).
__device__ __forceinline__ float cls_term_fast(float zz, float posin) {
    float e  = __expf(-fabsf(zz));
    float lg = __logf(1.f + e);
    float sp = (zz >= 0.f) ? lg : (lg - zz);   // softplus(-z)
    float r1 = 1.f / (1.f + e);
    float sn = (zz >= 0.f) ? e*r1 : r1;        // sigmoid(-z)
    float fp = 0.25f * sp * sn * sn;
    return 0.25f * fp * posin;
}

// ------- Kernel A: one block per batch — cost, global top-4, assign, losses -------
__global__ void __launch_bounds__(TA)
crit_all(const float* __restrict__ loc_out, const float* __restrict__ obj_logit,
         const float* __restrict__ cls_logit, const float* __restrict__ gt_loc,
         const float* __restrict__ gt_cls, float* __restrict__ ws)
{
    __shared__ float wv_val[NW][NN][4];
    __shared__ int   wv_idx[NW][NN][4];
    __shared__ float obj_s[NW];
    __shared__ float cand_val[NN][NN];
    __shared__ int   cand_idx[NN][NN];
    __shared__ int   s_pred[NN];
    __shared__ float s_best[4];
    __shared__ int   s_bestc[4];
    __shared__ float red[4];

    const int b   = blockIdx.x;
    const int tid = threadIdx.x;
    const int w   = tid >> 6, lane = tid & 63;

    // ---- sync-free GT class setup (one-hot, CC == 64 lanes); all waves redundant ----
    int   cls[NN]; float posin[NN];
    #pragma unroll
    for (int n = 0; n < NN; ++n) {
        float v = gt_cls[(b*NN+n)*CC + lane];
        unsigned long long m = __ballot(v > 0.5f);
        cls[n]   = __ffsll(m) - 1;
        posin[n] = 1.f / fmaxf((float)__popcll(m), 1.f);
    }

    // ---- gt vectors: uniform-address scalar loads ----
    float vt[NN][DD];
    #pragma unroll
    for (int n = 0; n < NN; ++n) {
        float g0 = gt_loc[(b*NN+n)*DD+0];
        float g1 = gt_loc[(b*NN+n)*DD+1];
        float g2 = gt_loc[(b*NN+n)*DD+2];
        float gin = 1.f / fmaxf(sqrtf(g0*g0 + g1*g1 + g2*g2), 1e-8f);
        vt[n][0] = g0*gin; vt[n][1] = g1*gin; vt[n][2] = g2*gin;
    }

    // ---- full cost for KPT k's per thread, register-resident ----
    float cost[KPT][NN];
    float obj_base = 0.f;
    #pragma unroll
    for (int j = 0; j < KPT; ++j) {
        const int k = tid + TA*j;
        const float* lp = loc_out + ((size_t)b*KK + k)*DD;
        float l0 = lp[0], l1 = lp[1], l2 = lp[2];
        float x  = obj_logit[b*KK + k];
        float inv = 1.f / fmaxf(sqrtf(l0*l0 + l1*l1 + l2*l2), 1e-8f);
        float v0 = l0*inv, v1 = l1*inv, v2 = l2*inv;
        obj_base += fmaxf(x, 0.f) + log1pf(expf(-fabsf(x)));    // LOSS: accurate
        float oc = -0.1f / (1.f + __expf(-x));                  // cost: fast
        #pragma unroll
        for (int n = 0; n < NN; ++n) {
            float cosv = v0*vt[n][0] + v1*vt[n][1] + v2*vt[n][2];
            cosv = fminf(fmaxf(cosv, -1.f + 1e-6f), 1.f - 1e-6f);
            float zz = cls_logit[((size_t)b*KK + k)*CC + cls[n]];
            cost[j][n] = acospi_fast(cosv) + cls_term_fast(zz, posin[n]) + oc;
        }
    }

    // obj: wave shfl-sum now (independent of LDS phases).
    {
        float osum = obj_base;
        #pragma unroll
        for (int off = 32; off > 0; off >>= 1) osum += __shfl_xor(osum, off, 64);
        if (lane == 0) obj_s[w] = osum;
    }

    // ---- per-wave top-4 per row (wave covers KPT*64 = 256 k's) ----
    #pragma unroll
    for (int n = 0; n < NN; ++n) {
        float vv[KPT]; int gi[KPT];
        #pragma unroll
        for (int j = 0; j < KPT; ++j) { vv[j] = cost[j][n]; gi[j] = tid + TA*j; }
        #pragma unroll
        for (int r = 0; r < 4; ++r) {
            float bv = vv[0]; int bi = gi[0];
            #pragma unroll
            for (int j = 1; j < KPT; ++j)
                if (vv[j] < bv || (vv[j] == bv && gi[j] < bi)) { bv = vv[j]; bi = gi[j]; }
            #pragma unroll
            for (int off = 32; off > 0; off >>= 1) {
                float ov = __shfl_xor(bv, off, 64);
                int   oi = __shfl_xor(bi, off, 64);
                if (ov < bv || (ov == bv && oi < bi)) { bv = ov; bi = oi; }
            }
            if (lane == 0) { wv_val[w][n][r] = bv; wv_idx[w][n][r] = bi; }
            #pragma unroll
            for (int j = 0; j < KPT; ++j) if (gi[j] == bi) vv[j] = INFINITY;
        }
    }
    __syncthreads();   // wv_* and obj_s visible

    // ---- merge: wave w (w<4) reduces row w's NW*4 = 32 candidates ----
    if (w < NN) {
        float v = INFINITY; int idx = INT_MAX;
        if (lane < NW*4) { v = wv_val[lane>>2][w][lane&3]; idx = wv_idx[lane>>2][w][lane&3]; }
        #pragma unroll
        for (int r = 0; r < 4; ++r) {
            float bv = v; int bi = idx;
            #pragma unroll
            for (int off = 32; off > 0; off >>= 1) {
                float ov = __shfl_xor(bv, off, 64);
                int   oi = __shfl_xor(bi, off, 64);
                if (ov < bv || (ov == bv && oi < bi)) { bv = ov; bi = oi; }
            }
            if (lane == 0) { cand_val[w][r] = bv; cand_idx[w][r] = bi; }
            if (idx == bi) v = INFINITY;   // mask winner
        }
    }
    __syncthreads();

    // ---- brute force: threads 0..255 evaluate combo tid (4x 2-bit fields) ----
    if (tid < 256) {
        int a0 = (tid >> 6) & 3, a1 = (tid >> 4) & 3, a2 = (tid >> 2) & 3, a3 = tid & 3;
        int c0 = cand_idx[0][a0], c1 = cand_idx[1][a1];
        int c2 = cand_idx[2][a2], c3 = cand_idx[3][a3];
        bool valid = (c0!=c1) & (c0!=c2) & (c0!=c3) & (c1!=c2) & (c1!=c3) & (c2!=c3);
        float t = cand_val[0][a0] + cand_val[1][a1] + cand_val[2][a2] + cand_val[3][a3];
        float bv = valid ? t : INFINITY;
        int   bc = tid;
        #pragma unroll
        for (int off = 32; off > 0; off >>= 1) {
            float ov = __shfl_xor(bv, off, 64);
            int   oc = __shfl_xor(bc, off, 64);
            if (ov < bv || (ov == bv && oc < bc)) { bv = ov; bc = oc; }
        }
        if (lane == 0) { s_best[w] = bv; s_bestc[w] = bc; }
    }
    __syncthreads();

    if (tid == 0) {
        float bv = s_best[0]; int bc = s_bestc[0];
        for (int i = 1; i < 4; ++i)
            if (s_best[i] < bv || (s_best[i] == bv && s_bestc[i] < bc)) { bv = s_best[i]; bc = s_bestc[i]; }
        int a0 = (bc >> 6) & 3, a1 = (bc >> 4) & 3, a2 = (bc >> 2) & 3, a3 = bc & 3;
        s_pred[0] = cand_idx[0][a0]; s_pred[1] = cand_idx[1][a1];
        s_pred[2] = cand_idx[2][a2]; s_pred[3] = cand_idx[3][a3];

        // obj partial: block total minus matched logits (accurate path)
        float om = 0.f;
        for (int i = 0; i < NW; ++i) om += obj_s[i];
        for (int n = 0; n < NN; ++n) om -= obj_logit[b*KK + s_pred[n]];
        ws[b*3 + 2] = om;

        // loc partial (12 terms, L2/L3-hot)
        float s = 0.f;
        for (int n = 0; n < NN; ++n)
            for (int d = 0; d < DD; ++d) {
                float diff = loc_out[((size_t)b*KK + s_pred[n])*DD + d] - gt_loc[(b*NN+n)*DD + d];
                s += diff*diff;
            }
        ws[b*3 + 0] = s;
    }
    __syncthreads();

    // ---- cls partial: waves 0..3 = rows, lane = class; accurate focal BCE ----
    if (w < NN) {
        int n = w, c = lane;
        float zz = cls_logit[((size_t)b*KK + s_pred[n])*CC + c];
        float tgt = (c == cls[n]) ? 1.f : 0.f;
        float p  = 1.f / (1.f + expf(-zz));
        float ce = fmaxf(zz, 0.f) - zz*tgt + log1pf(expf(-fabsf(zz)));
        float pt = p*tgt + (1.f-p)*(1.f-tgt);
        float at = 0.25f*tgt + 0.75f*(1.f-tgt);
        float om1 = 1.f - pt;
        float r = at * ce * om1 * om1;
        #pragma unroll
        for (int off = 32; off > 0; off >>= 1) r += __shfl_xor(r, off, 64);
        if (lane == 0) red[n] = r;
    }
    __syncthreads();
    if (tid == 0) ws[b*3 + 1] = red[0] + red[1] + red[2] + red[3];
}

// ---------------- Kernel C: deterministic final reduction ----------------
__global__ void __launch_bounds__(BB)
crit_final(const float* __restrict__ ws, float* __restrict__ out)
{
    __shared__ float s2[3][2];
    int t = threadIdx.x;
    int w = t >> 6, lane = t & 63;
    float a = ws[t*3+0];
    float b = ws[t*3+1];
    float c = ws[t*3+2];
    #pragma unroll
    for (int off = 32; off > 0; off >>= 1) {
        a += __shfl_xor(a, off, 64);
        b += __shfl_xor(b, off, 64);
        c += __shfl_xor(c, off, 64);
    }
    if (lane == 0) { s2[0][w] = a; s2[1][w] = b; s2[2][w] = c; }
    __syncthreads();
    if (t == 0) {
        out[0] = (s2[0][0]+s2[0][1]) / (float)(BB*NN*DD)
               + (s2[1][0]+s2[1][1]) / (float)(BB*NN*CC)
               + (s2[2][0]+s2[2][1]) / (float)(BB*KK);
    }
}

extern "C" void kernel_launch(void* const* d_in, const int* in_sizes, int n_in,
                              void* d_out, int out_size, void* d_ws, size_t ws_size,
                              hipStream_t stream) {
    const float* loc_out   = (const float*)d_in[0];
    const float* obj_logit = (const float*)d_in[1];
    const float* cls_logit = (const float*)d_in[2];
    const float* gt_loc    = (const float*)d_in[3];
    const float* gt_cls    = (const float*)d_in[4];
    float* ws  = (float*)d_ws;
    float* out = (float*)d_out;

    hipLaunchKernelGGL(crit_all, dim3(BB), dim3(TA), 0, stream,
                       loc_out, obj_logit, cls_logit, gt_loc, gt_cls, ws);
    hipLaunchKernelGGL(crit_final, dim3(1), dim3(BB), 0, stream, ws, out);
}

// Round 10
// 27.796 us; speedup vs baseline: 1.3231x; 1.3231x over previous
//
#include <hip/hip_runtime.h>
#include <math.h>
#include <limits.h>

#define BB 128
#define KK 2048
#define NN 4
#define CC 64
#define DD 3
#define SL 8            // K-slices per batch
#define KS (KK/SL)      // 256 k per slice
#define THREADS 256

// ws layout (float words):
#define OFF_CVAL 0
#define OFF_CIDX (BB*SL*NN*NN)
#define OFF_OBJ  (2*BB*SL*NN*NN)

// ---- fast approximations: COST MATRIX ONLY (losses use accurate libm) ----
__device__ __forceinline__ float acospi_fast(float x) {
    // Hastings: acos(x) ~ sqrt(1-x)*p(x), abs err ~6.7e-5 rad; divided by pi.
    float ax = fabsf(x);
    float p = ((-0.0187293f*ax + 0.0742610f)*ax - 0.2121144f)*ax + 1.5707288f;
    float r = sqrtf(1.f - ax) * p;
    r = (x >= 0.f) ? r : 3.14159274f - r;
    return r * 0.31830988618379067f;
}

// ---------------- Kernel A: cost + per-slice top-4 per GT row ----------------
__global__ void __launch_bounds__(THREADS)
crit_cost(const float* __restrict__ loc_out, const float* __restrict__ obj_logit,
          const float* __restrict__ cls_logit, const float* __restrict__ gt_loc,
          const float* __restrict__ gt_cls, float* __restrict__ ws,
          float* __restrict__ out)
{
    __shared__ float cost[NN][KS];     // 4 KB
    __shared__ float obj_s[4];

    const int sl  = blockIdx.x;
    const int b   = blockIdx.y;
    const int tid = threadIdx.x;
    const int w   = tid >> 6, lane = tid & 63;
    const int k   = sl*KS + tid;

    // Zero the output accumulator (single writer; visible to kernel B at the
    // kernel boundary). No extra memset dispatch needed.
    if (sl == 0 && b == 0 && tid == 0) out[0] = 0.f;

    // ---- issue primary loads early ----
    const float* lp = loc_out + ((size_t)b*KK + k)*DD;
    float l0 = lp[0], l1 = lp[1], l2 = lp[2];
    float x  = obj_logit[b*KK + k];

    // ---- sync-free GT class setup: gt_cls is exact one-hot, CC == 64 lanes ----
    int   cls[NN]; float posin[NN];
    #pragma unroll
    for (int n = 0; n < NN; ++n) {
        float v = gt_cls[(b*NN+n)*CC + lane];
        unsigned long long m = __ballot(v > 0.5f);
        cls[n]   = __ffsll(m) - 1;
        posin[n] = 1.f / fmaxf((float)__popcll(m), 1.f);
    }

    // ---- issue the 4 strided cls gathers ASAP (the latency hog) ----
    float z[NN];
    #pragma unroll
    for (int n = 0; n < NN; ++n)
        z[n] = cls_logit[((size_t)b*KK + k)*CC + cls[n]];

    // ---- gt vectors: uniform-address scalar loads ----
    float vt[NN][DD];
    #pragma unroll
    for (int n = 0; n < NN; ++n) {
        float g0 = gt_loc[(b*NN+n)*DD+0];
        float g1 = gt_loc[(b*NN+n)*DD+1];
        float g2 = gt_loc[(b*NN+n)*DD+2];
        float gin = 1.f / fmaxf(sqrtf(g0*g0 + g1*g1 + g2*g2), 1e-8f);
        vt[n][0] = g0*gin; vt[n][1] = g1*gin; vt[n][2] = g2*gin;
    }

    // ---- math (overlaps with in-flight gathers) ----
    float inv = 1.f / fmaxf(sqrtf(l0*l0 + l1*l1 + l2*l2), 1e-8f);
    float v0 = l0*inv, v1 = l1*inv, v2 = l2*inv;
    float obj_base = fmaxf(x, 0.f) + log1pf(expf(-fabsf(x)));   // LOSS: accurate
    float oc = -0.1f / (1.f + __expf(-x));                      // cost: fast
    #pragma unroll
    for (int n = 0; n < NN; ++n) {
        float cosv = v0*vt[n][0] + v1*vt[n][1] + v2*vt[n][2];
        cosv = fminf(fmaxf(cosv, -1.f + 1e-6f), 1.f - 1e-6f);
        float loc_c = acospi_fast(cosv);
        float zz = z[n];
        float e  = __expf(-fabsf(zz));
        float lg = __logf(1.f + e);
        float sp = (zz >= 0.f) ? lg : (lg - zz);                // softplus(-z)
        float r1 = 1.f / (1.f + e);
        float sn = (zz >= 0.f) ? e*r1 : r1;                     // sigmoid(-z)
        float fp = 0.25f * sp * sn * sn;
        cost[n][tid] = loc_c + 0.25f*fp*posin[n] + oc;
    }

    // obj partial: wave shfl-sum, 4-wave combine.
    float osum = obj_base;
    #pragma unroll
    for (int off = 32; off > 0; off >>= 1) osum += __shfl_xor(osum, off, 64);
    if (lane == 0) obj_s[w] = osum;
    __syncthreads();   // cost[][] + obj_s visible

    // ---- per-slice top-4 of row w (wave-synchronous) ----
    float vv[4]; int gi[4];
    #pragma unroll
    for (int j = 0; j < 4; ++j) {
        vv[j] = cost[w][lane + 64*j];
        gi[j] = sl*KS + lane + 64*j;
    }
    float cr_val[NN]; int cr_idx[NN];
    #pragma unroll
    for (int r = 0; r < NN; ++r) {
        float bv = vv[0]; int bi = gi[0];
        #pragma unroll
        for (int j = 1; j < 4; ++j)
            if (vv[j] < bv || (vv[j] == bv && gi[j] < bi)) { bv = vv[j]; bi = gi[j]; }
        #pragma unroll
        for (int off = 32; off > 0; off >>= 1) {
            float ov = __shfl_xor(bv, off, 64);
            int   oi = __shfl_xor(bi, off, 64);
            if (ov < bv || (ov == bv && oi < bi)) { bv = ov; bi = oi; }
        }
        cr_val[r] = bv; cr_idx[r] = bi;
        #pragma unroll
        for (int j = 0; j < 4; ++j) if (gi[j] == bi) vv[j] = INFINITY;
    }
    if (lane == 0) {
        int base = ((b*SL + sl)*NN + w)*NN;
        int* wsi = (int*)ws;
        #pragma unroll
        for (int r = 0; r < NN; ++r) {
            ws[OFF_CVAL + base + r]  = cr_val[r];
            wsi[OFF_CIDX + base + r] = cr_idx[r];
        }
    }
    if (tid == 0)
        ws[OFF_OBJ + b*SL + sl] = obj_s[0] + obj_s[1] + obj_s[2] + obj_s[3];
}

// ------- Kernel B: merge candidates, assign, weighted loss -> one atomicAdd -------
__global__ void __launch_bounds__(THREADS)
crit_match(const float* __restrict__ loc_out, const float* __restrict__ obj_logit,
           const float* __restrict__ cls_logit, const float* __restrict__ gt_loc,
           const float* __restrict__ gt_cls, float* __restrict__ ws,
           float* __restrict__ out)
{
    __shared__ float cand_val[NN][NN];
    __shared__ int   cand_idx[NN][NN];
    __shared__ int   s_pred[NN];
    __shared__ float s_best[4];
    __shared__ int   s_bestc[4];
    __shared__ float red[4];
    __shared__ float s_lo;      // weighted loc+obj contribution

    const int b = blockIdx.x, tid = threadIdx.x;
    const int w = tid >> 6, lane = tid & 63;
    const int* wsi = (const int*)ws;

    // Merge: wave w holds the SL*NN = 32 candidates of row w in lanes 0..31.
    {
        float v = INFINITY; int idx = INT_MAX;
        if (lane < SL*NN) {
            int sl = lane >> 2, r = lane & 3;
            int base = ((b*SL + sl)*NN + w)*NN + r;
            v   = ws[OFF_CVAL + base];
            idx = wsi[OFF_CIDX + base];
        }
        #pragma unroll
        for (int r = 0; r < NN; ++r) {
            float bv = v; int bi = idx;
            #pragma unroll
            for (int off = 32; off > 0; off >>= 1) {
                float ov = __shfl_xor(bv, off, 64);
                int   oi = __shfl_xor(bi, off, 64);
                if (ov < bv || (ov == bv && oi < bi)) { bv = ov; bi = oi; }
            }
            if (lane == 0) { cand_val[w][r] = bv; cand_idx[w][r] = bi; }
            if (idx == bi) v = INFINITY;   // mask winner
        }
    }
    __syncthreads();

    // Brute force: thread tid evaluates combo tid (a0..a3 = 2-bit fields).
    {
        int a0 = (tid >> 6) & 3, a1 = (tid >> 4) & 3, a2 = (tid >> 2) & 3, a3 = tid & 3;
        int c0 = cand_idx[0][a0], c1 = cand_idx[1][a1];
        int c2 = cand_idx[2][a2], c3 = cand_idx[3][a3];
        bool valid = (c0!=c1) & (c0!=c2) & (c0!=c3) & (c1!=c2) & (c1!=c3) & (c2!=c3);
        float t = cand_val[0][a0] + cand_val[1][a1] + cand_val[2][a2] + cand_val[3][a3];
        float bv = valid ? t : INFINITY;
        int   bc = tid;
        #pragma unroll
        for (int off = 32; off > 0; off >>= 1) {
            float ov = __shfl_xor(bv, off, 64);
            int   oc = __shfl_xor(bc, off, 64);
            if (ov < bv || (ov == bv && oc < bc)) { bv = ov; bc = oc; }
        }
        if (lane == 0) { s_best[w] = bv; s_bestc[w] = bc; }
    }
    __syncthreads();

    if (tid == 0) {
        float bv = s_best[0]; int bc = s_bestc[0];
        for (int i = 1; i < 4; ++i)
            if (s_best[i] < bv || (s_best[i] == bv && s_bestc[i] < bc)) { bv = s_best[i]; bc = s_bestc[i]; }
        int a0 = (bc >> 6) & 3, a1 = (bc >> 4) & 3, a2 = (bc >> 2) & 3, a3 = bc & 3;
        s_pred[0] = cand_idx[0][a0]; s_pred[1] = cand_idx[1][a1];
        s_pred[2] = cand_idx[2][a2]; s_pred[3] = cand_idx[3][a3];

        // obj partial (accurate)
        float om = 0.f;
        for (int sl = 0; sl < SL; ++sl) om += ws[OFF_OBJ + b*SL + sl];
        for (int n = 0; n < NN; ++n) om -= obj_logit[b*KK + s_pred[n]];

        // loc partial (12 terms)
        float s = 0.f;
        for (int n = 0; n < NN; ++n)
            for (int d = 0; d < DD; ++d) {
                float diff = loc_out[((size_t)b*KK + s_pred[n])*DD + d] - gt_loc[(b*NN+n)*DD + d];
                s += diff*diff;
            }
        s_lo = s / (float)(BB*NN*DD) + om / (float)(BB*KK);
    }
    __syncthreads();

    // cls partial: 256 threads = 4 rows x 64 classes; accurate focal BCE.
    {
        int n = w, c = lane;
        float zz = cls_logit[((size_t)b*KK + s_pred[n])*CC + c];
        float tgt = gt_cls[(b*NN+n)*CC + c];
        float p  = 1.f / (1.f + expf(-zz));
        float ce = fmaxf(zz, 0.f) - zz*tgt + log1pf(expf(-fabsf(zz)));
        float pt = p*tgt + (1.f-p)*(1.f-tgt);
        float at = 0.25f*tgt + 0.75f*(1.f-tgt);
        float om1 = 1.f - pt;
        float r = at * ce * om1 * om1;
        #pragma unroll
        for (int off = 32; off > 0; off >>= 1) r += __shfl_xor(r, off, 64);
        if (lane == 0) red[n] = r;
    }
    __syncthreads();

    // One relaxed float atomic per block: fully-weighted batch contribution.
    if (tid == 0) {
        float total = s_lo + (red[0] + red[1] + red[2] + red[3]) / (float)(BB*NN*CC);
        atomicAdd(out, total);
    }
}

extern "C" void kernel_launch(void* const* d_in, const int* in_sizes, int n_in,
                              void* d_out, int out_size, void* d_ws, size_t ws_size,
                              hipStream_t stream) {
    const float* loc_out   = (const float*)d_in[0];
    const float* obj_logit = (const float*)d_in[1];
    const float* cls_logit = (const float*)d_in[2];
    const float* gt_loc    = (const float*)d_in[3];
    const float* gt_cls    = (const float*)d_in[4];
    float* ws  = (float*)d_ws;
    float* out = (float*)d_out;

    hipLaunchKernelGGL(crit_cost, dim3(SL, BB), dim3(THREADS), 0, stream,
                       loc_out, obj_logit, cls_logit, gt_loc, gt_cls, ws, out);
    hipLaunchKernelGGL(crit_match, dim3(BB), dim3(THREADS), 0, stream,
                       loc_out, obj_logit, cls_logit, gt_loc, gt_cls, ws, out);
}